// Round 1
// baseline (330.588 us; speedup 1.0000x reference)
//
#include <hip/hip_runtime.h>

// Problem constants (from reference):
//   B=64, S=128, T=16, E_ELMO=1024, D_TRI=100, out row = 1124 f32
constexpr int Bc = 64;
constexpr int Sc = 128;
constexpr int Tc = 16;
constexpr int Ec = 1024;       // token embedding dim (256 float4)
constexpr int Dc = 100;        // entity embedding dim (400 B rows, 8B-aligned as float2)
constexpr int OUTD = Ec + Dc;  // 1124 (row stride 4496 B, 16B-aligned)
constexpr int TOK_PER_BLOCK = 4;  // one wave (64 lanes) per token, 4 waves/block

// Barrier-free design: each wave independently owns one token.
//  - lanes 0..15 load id2 + BOTH triple candidates in parallel (no dependent
//    id2->triples round trip), select after arrival
//  - slot->entity broadcast via __ballot/__shfl (no LDS, no __syncthreads,
//    so the 4KB emb-row copy is never drained by a barrier and overlaps the
//    entity gathers)
//  - gather: lanes 0..49 each own a float2 of the 100-dim entity row; fixed
//    16-iter unroll keeps all loads independent (pad slots read L1-hot row 0)
__global__ __launch_bounds__(256) void triple_fuse_wave(
    const int*   __restrict__ inputs,   // [B*S]
    const int*   __restrict__ triples,  // [B*S*T*3]
    const int*   __restrict__ id2,      // [B*S*T]
    const float* __restrict__ emb,      // [VOCAB*E]
    const float* __restrict__ ent,      // [ENT_VOCAB*D]
    float*       __restrict__ out)      // [B*S*OUTD]
{
    const int lane  = threadIdx.x & 63;
    const int token = blockIdx.x * TOK_PER_BLOCK + (threadIdx.x >> 6);

    // ---- trip 1: all first-level loads issued independently ----
    int trow = inputs[token];           // wave-uniform address -> broadcast
    int flag = 0, head = 0, tail = 0;
    if (lane < Tc) {
        const int slot = token * Tc + lane;
        flag = id2[slot];               // three independent loads, one round trip
        head = triples[slot * 3 + 0];
        tail = triples[slot * 3 + 1];
    }
    trow = __builtin_amdgcn_readfirstlane(trow);  // scalar base for emb row

    // ---- trip 2a: token-embedding row copy, 4 KB per wave ----
    const float4* __restrict__ erow = (const float4*)(emb + (long)trow * Ec);
    const float4 t0 = erow[lane];
    const float4 t1 = erow[lane + 64];
    const float4 t2 = erow[lane + 128];
    const float4 t3 = erow[lane + 192];

    // ---- decode: lane j<16 owns slot j; e = entity row or -1 ----
    int e = -1;
    if (lane < Tc) e = (flag == 1) ? tail : ((flag == 2) ? head : -1);
    const unsigned long long m = __ballot(e >= 0);
    const int cnt = (int)__popcll(m);   // wave-uniform, no shuffle needed

    float* __restrict__ orow = out + (long)token * OUTD;

    // ---- trip 2b (overlaps 2a): entity gather+average, float2 per lane ----
    if (lane < 50) {
        const float2* __restrict__ ent2 = (const float2*)ent;
        float sx = 0.f, sy = 0.f;
        #pragma unroll
        for (int j = 0; j < Tc; ++j) {
            const int ej  = __shfl(e, j);        // source lanes 0..15 are active
            const int row = (ej >= 0) ? ej : 0;  // pad slots: L1-hot row 0
            const float2 v = ent2[(long)row * 50 + lane];
            if (ej >= 0) { sx += v.x; sy += v.y; }   // cndmask-predicated adds
        }
        float2 r;
        if (cnt > 0) { const float c = (float)cnt; r.x = sx / c; r.y = sy / c; }
        else         { r.x = 0.f;  r.y = 0.f; }
        *(float2*)(orow + Ec + 2 * lane) = r;
    }

    // ---- token part store (t-loads have long since landed) ----
    float4* __restrict__ o4 = (float4*)orow;
    o4[lane]       = t0;
    o4[lane + 64]  = t1;
    o4[lane + 128] = t2;
    o4[lane + 192] = t3;
}

extern "C" void kernel_launch(void* const* d_in, const int* in_sizes, int n_in,
                              void* d_out, int out_size, void* d_ws, size_t ws_size,
                              hipStream_t stream) {
    const int*   inputs  = (const int*)d_in[0];
    const int*   triples = (const int*)d_in[1];
    const int*   id2     = (const int*)d_in[2];
    const float* emb     = (const float*)d_in[3];
    const float* ent     = (const float*)d_in[4];
    float*       out     = (float*)d_out;

    triple_fuse_wave<<<(Bc * Sc) / TOK_PER_BLOCK, 256, 0, stream>>>(
        inputs, triples, id2, emb, ent, out);
}